// Round 7
// baseline (1117.626 us; speedup 1.0000x reference)
//
#include <hip/hip_runtime.h>

// ---------------------------------------------------------------------------
// Two-layer tanh RNN — round 9: lgkm-only barriers + remote-h prefetch.
// B=64, T=512, H=512, I=128, W_OUT=32. fp32 in/out, f16-pair internal, fp32 acc.
//
// Base = round-8 champion (per-wave private chunks, readiness-split dots,
// 64 clusters = layer x pair, 4 sibling WGs x 1024 thr, 1 WG/CU, tagged
// {tag|f16pair} atoms RELAXED agent scope, DRING=256 + throttle, epoch tags,
// FC in L1 s==0). Round-9 changes:
//  (1) Main-loop barriers are s_waitcnt lgkmcnt(0); s_barrier — NOT
//      __syncthreads() (which drains vmcnt(0), forcing the fire-and-forget
//      atomic posts + noise/h prefetch loads to complete at every barrier,
//      ~2x store-ack latency per step). LDS visibility (psum/hown) only
//      needs lgkmcnt. Atomic posts have no ordering requirement (consumers
//      poll tags); prefetch loads are compiler-waited at their use.
//  (2) Remote-h gathers (L0 w<12: sibling h0; L1 w10-15: sibling h1) are
//      PREFETCHED at the bottom of step t (just after barrier c, when the
//      siblings' reduce has posted), tag-checked at stage(t+1), poll only
//      on miss. Converts the common case from ~2xRTT (cold poll, each retry
//      = full load latency) to ~0-1xRTT.
// Roles: L0: w0-11 remote-h0 (6 chunks x 2 batch-waves), w12-13 own-h0,
//        w14-15 x. L1: w0-7 h0 (prefetch), w8-9 own-h1, w10-15 remote-h1.
// ---------------------------------------------------------------------------

#define T_STEPS 512
#define NBATCH  64
#define DRING   256
#define THR_LEAD 192

typedef _Float16 half2v __attribute__((ext_vector_type(2)));

__device__ __forceinline__ unsigned pack2(float a, float b) {
    _Float16 fa = (_Float16)a, fb = (_Float16)b;
    unsigned short ua = __builtin_bit_cast(unsigned short, fa);
    unsigned short ub = __builtin_bit_cast(unsigned short, fb);
    return (unsigned)ua | ((unsigned)ub << 16);
}

__device__ __forceinline__ float dot2acc(unsigned w, unsigned h, float acc) {
#if __has_builtin(__builtin_amdgcn_fdot2)
    return __builtin_amdgcn_fdot2(__builtin_bit_cast(half2v, w),
                                  __builtin_bit_cast(half2v, h), acc, false);
#else
    half2v wv = __builtin_bit_cast(half2v, w);
    half2v hv = __builtin_bit_cast(half2v, h);
    acc = fmaf((float)wv.x, (float)hv.x, acc);
    return fmaf((float)wv.y, (float)hv.y, acc);
#endif
}

__device__ __forceinline__ float fast_tanh(float xv) {
    float e2 = __builtin_amdgcn_exp2f(xv * 2.885390082f);
    return 1.f - 2.f * __builtin_amdgcn_rcpf(e2 + 1.f);
}

// Workgroup barrier with LDS-only drain (posts/prefetches stay in flight).
__device__ __forceinline__ void bar_lgkm() {
    asm volatile("s_waitcnt lgkmcnt(0)\n\ts_barrier" ::: "memory");
}

__device__ __forceinline__ unsigned poll1(unsigned long long* p, unsigned tag,
                                          long& budget) {
    unsigned long long v = __hip_atomic_load(p, __ATOMIC_RELAXED, __HIP_MEMORY_SCOPE_AGENT);
    while ((unsigned)(v >> 32) != tag && budget > 0) {
        v = __hip_atomic_load(p, __ATOMIC_RELAXED, __HIP_MEMORY_SCOPE_AGENT);
        --budget;
    }
    return (unsigned)v;
}

// Packed weights: wp[(base + rr*32 + j)*64 + lane], row r = s*128 + 2*lane + rr.
// L0 base = (s*10 + cs)*64: cs 0-5 remote-h0 (m=cs*32+j, p0 = m<s*64?m:m+64),
//   cs 6-7 own-h0 (p0 = s*64+(cs-6)*32+j), cs 8-9 x (px=(cs-8)*32+j).
// L1 base = (s*16 + w)*64: w0-7 h0 (p=w*32+j), w8-9 own-h1, w10-15 remote-h1.
#define NW0 (4 * 10 * 64 * 64)
#define NW1 (4 * 16 * 64 * 64)

__global__ void init_pack(const float* __restrict__ Wih0, const float* __restrict__ Whh0,
                          const float* __restrict__ Wih1, const float* __restrict__ Whh1,
                          unsigned* __restrict__ wp0, unsigned* __restrict__ wp1,
                          int* __restrict__ prog) {
    int gid = blockIdx.x * 256 + threadIdx.x;
    if (gid == 32) prog[32] = prog[32] + 1;   // epoch bump (replay-unique tags)
    if (gid < 32) prog[gid] = 0;
    if (gid < NW0) {
        int lane = gid & 63, slot = (gid >> 6) & 63, t12 = gid >> 12;
        int cs = t12 % 10, s = t12 / 10;
        int rr = slot >> 5, j = slot & 31;
        int r = s * 128 + 2 * lane + rr;
        float w0, w1;
        if (cs < 6)      { int m = cs * 32 + j; int p0 = (m < s * 64) ? m : m + 64;
                           w0 = Whh0[r * 512 + 2 * p0]; w1 = Whh0[r * 512 + 2 * p0 + 1]; }
        else if (cs < 8) { int p0 = s * 64 + (cs - 6) * 32 + j;
                           w0 = Whh0[r * 512 + 2 * p0]; w1 = Whh0[r * 512 + 2 * p0 + 1]; }
        else             { int px = (cs - 8) * 32 + j;
                           w0 = Wih0[r * 128 + 2 * px]; w1 = Wih0[r * 128 + 2 * px + 1]; }
        wp0[gid] = pack2(w0, w1);
    } else if (gid < NW0 + NW1) {
        int g2 = gid - NW0;
        int lane = g2 & 63, slot = (g2 >> 6) & 63, w = (g2 >> 12) & 15, s = g2 >> 16;
        int rr = slot >> 5, j = slot & 31;
        int r = s * 128 + 2 * lane + rr;
        float w0, w1;
        if (w < 8)       { int p = w * 32 + j;
                           w0 = Wih1[r * 512 + 2 * p]; w1 = Wih1[r * 512 + 2 * p + 1]; }
        else if (w < 10) { int p1 = s * 64 + (w - 8) * 32 + j;
                           w0 = Whh1[r * 512 + 2 * p1]; w1 = Whh1[r * 512 + 2 * p1 + 1]; }
        else             { int m = (w - 10) * 32 + j; int p1 = (m < s * 64) ? m : m + 64;
                           w0 = Whh1[r * 512 + 2 * p1]; w1 = Whh1[r * 512 + 2 * p1 + 1]; }
        wp1[g2] = pack2(w0, w1);
    }
}

template <int LAYER>
__device__ __forceinline__ void run_layer(
    int b0, int s, int L, int pair,
    const float* __restrict__ x, const float* __restrict__ noise,
    const unsigned* __restrict__ wp,
    const float* __restrict__ bih, const float* __restrict__ bhh,
    unsigned long long* __restrict__ hb0, unsigned long long* __restrict__ hb1,
    int* __restrict__ prog,
    const float* __restrict__ fcw, const float* __restrict__ fcb,
    float* __restrict__ out) {
    const int w = L >> 6, lane = L & 63;
    const unsigned tagbase = ((unsigned)prog[32]) << 10;
    long budget = 2000000000L;

    // ---- persistent weights: 64 dwords/lane (2 rows x 32 pairs) ----
    int wbase;
    if constexpr (LAYER == 0) { int cs = (w < 12) ? (w >> 1) : (w - 6); wbase = (s * 10 + cs) * 64; }
    else                      { wbase = (s * 16 + w) * 64; }
    unsigned wreg[64];
#pragma unroll
    for (int i = 0; i < 64; ++i) {
        wreg[i] = wp[(size_t)(wbase + i) * 64 + lane];
        asm volatile("" : "+v"(wreg[i]));
    }

    __shared__ float psum[16][2][128];                 // [chunk][batch][row]
    __shared__ __align__(16) unsigned priv[16][64];    // per-wave strips
    __shared__ __align__(16) unsigned hown[128];       // own pairs [p_local*2+bb]
    for (int i = L; i < 16 * 64; i += 1024) ((unsigned*)priv)[i] = 0u;
    if (L < 128) hown[L] = 0u;                         // h(-1) = 0

    // reduce-role constants (lanes 0..255: bb = L>>7, row rw = L&127)
    const bool isRed = (L < 256);
    const int bbr = L >> 7, rw = L & 127;
    const int rgl = s * 128 + rw;
    float cb = 0.f, nz = 0.f;
    if (isRed) {
        cb = bih[rgl] + bhh[rgl];
        nz = noise[(((size_t)(b0 + bbr) * T_STEPS + 0) * 2 + LAYER) * 512 + rgl];
    }
    __syncthreads();

    // ---- pre-loop staging ----
    unsigned long long pf = 0;    // L1 w<8: h0 prefetch
    unsigned long long pfR = 0;   // remote-h prefetch (L0 w<12 / L1 w10-15)
    float2 xf = make_float2(0.f, 0.f);
    if constexpr (LAYER == 1) {
        if (w < 8) {   // h0(0): blocking poll (L0 computes it in its step 0)
            unsigned v = poll1(&hb0[((size_t)0 * NBATCH + (b0 + (lane >> 5))) * 256 +
                                    (w * 32 + (lane & 31))], tagbase + 1, budget);
            pf = ((unsigned long long)(tagbase + 1) << 32) | v;
        }
    } else {
        if (w >= 14) {
            int j = lane & 31, bbl = lane >> 5;
            int px = (w - 14) * 32 + j;
            xf = *(const float2*)(x + ((size_t)(b0 + bbl) * T_STEPS + 0) * 128 + 2 * px);
        }
    }

    int known = 0;

    for (int t = 0; t < T_STEPS; ++t) {
        const bool last = (t == T_STEPS - 1);
        __builtin_amdgcn_s_setprio(1);

        // ---- per-wave staging (A: instant; B: prefetched, poll on miss) ----
        if constexpr (LAYER == 1) {
            if (w < 8) {                                  // h0(t): confirm prefetch
                const int j = lane & 31, bbl = lane >> 5;
                unsigned want = tagbase + (unsigned)t + 1;
                if ((unsigned)(pf >> 32) != want) {
                    __builtin_amdgcn_s_setprio(0);
                    unsigned v = poll1(&hb0[((size_t)(t & (DRING - 1)) * NBATCH + (b0 + bbl)) * 256 +
                                            (w * 32 + j)], want, budget);
                    pf = ((unsigned long long)want << 32) | v;
                    __builtin_amdgcn_s_setprio(1);
                }
                priv[w][j * 2 + bbl] = (unsigned)pf;
                if (!last)                                 // issue next prefetch
                    pf = __hip_atomic_load(&hb0[((size_t)((t + 1) & (DRING - 1)) * NBATCH +
                                                 (b0 + bbl)) * 256 + (w * 32 + j)],
                                           __ATOMIC_RELAXED, __HIP_MEMORY_SCOPE_AGENT);
            } else if (w >= 10) {                         // remote h1(t-1)
                if (t > 0) {
                    const int j = lane & 31, bbl = lane >> 5;
                    int m = (w - 10) * 32 + j;
                    int p2 = (m < s * 64) ? m : m + 64;
                    unsigned want = tagbase + (unsigned)t;
                    unsigned v;
                    if ((unsigned)(pfR >> 32) == want) {
                        v = (unsigned)pfR;
                    } else {
                        __builtin_amdgcn_s_setprio(0);
                        v = poll1(&hb1[((size_t)((t - 1) & 3) * NBATCH + (b0 + bbl)) * 256 + p2],
                                  want, budget);
                        __builtin_amdgcn_s_setprio(1);
                    }
                    priv[w][j * 2 + bbl] = v;
                }
            }
        } else {
            if (w < 12) {                                 // remote h0(t-1), 1 batch/wave
                if (t > 0 && lane < 32) {
                    int q = w >> 1, bbw = w & 1;
                    int m = q * 32 + lane;
                    int p2 = (m < s * 64) ? m : m + 64;
                    unsigned want = tagbase + (unsigned)t;
                    unsigned v;
                    if ((unsigned)(pfR >> 32) == want) {
                        v = (unsigned)pfR;
                    } else {
                        __builtin_amdgcn_s_setprio(0);
                        v = poll1(&hb0[((size_t)((t - 1) & (DRING - 1)) * NBATCH +
                                        (b0 + bbw)) * 256 + p2],
                                  want, budget);
                        __builtin_amdgcn_s_setprio(1);
                    }
                    priv[w][lane] = v;
                }
            } else if (w >= 14) {                         // x(t) pack + x(t+1) prefetch
                const int j = lane & 31, bbl = lane >> 5;
                priv[w][j * 2 + bbl] = pack2(xf.x, xf.y);
                if (!last) {
                    int px = (w - 14) * 32 + j;
                    xf = *(const float2*)(x + ((size_t)(b0 + bbl) * T_STEPS + (t + 1)) * 128 + 2 * px);
                }
            }
        }

        float nznext = 0.f;
        if (!last && isRed)
            nznext = noise[(((size_t)(b0 + bbr) * T_STEPS + (t + 1)) * 2 + LAYER) * 512 + rgl];

        // ---- dots: each wave, its chunk, 2 rows/lane ----
        if constexpr (LAYER == 0) {
            if (w < 12) {                                 // single batch
                const int q = w >> 1, bbw = w & 1;
                const uint4* hq = (const uint4*)&priv[w][0];   // 8 uint4, [pair]
                float ax[2] = {0.f, 0.f}, ay[2] = {0.f, 0.f};
#pragma unroll
                for (int k = 0; k < 8; ++k) {
                    uint4 v = hq[k];
#pragma unroll
                    for (int r2 = 0; r2 < 2; ++r2) {
                        ax[r2] = dot2acc(wreg[r2 * 32 + 4 * k + 0], v.x, ax[r2]);
                        ay[r2] = dot2acc(wreg[r2 * 32 + 4 * k + 1], v.y, ay[r2]);
                        ax[r2] = dot2acc(wreg[r2 * 32 + 4 * k + 2], v.z, ax[r2]);
                        ay[r2] = dot2acc(wreg[r2 * 32 + 4 * k + 3], v.w, ay[r2]);
                    }
                }
                *(float2*)&psum[q][bbw][2 * lane] =
                    make_float2(ax[0] + ay[0], ax[1] + ay[1]);
            } else {                                      // own-h0 / x: both batches
                const uint4* hq = (w < 14) ? (const uint4*)&hown[(w - 12) * 64]
                                           : (const uint4*)&priv[w][0];
                const int pidx = (w < 14) ? (6 + (w - 12)) : (8 + (w - 14));
                float a[2][2] = {{0.f, 0.f}, {0.f, 0.f}};
                float b2[2][2] = {{0.f, 0.f}, {0.f, 0.f}};
#pragma unroll
                for (int k = 0; k < 16; ++k) {
                    uint4 v = hq[k];
                    const int j0 = 2 * k, j1 = 2 * k + 1;
#pragma unroll
                    for (int r2 = 0; r2 < 2; ++r2) {
                        a[r2][0]  = dot2acc(wreg[r2 * 32 + j0], v.x, a[r2][0]);
                        a[r2][1]  = dot2acc(wreg[r2 * 32 + j0], v.y, a[r2][1]);
                        b2[r2][0] = dot2acc(wreg[r2 * 32 + j1], v.z, b2[r2][0]);
                        b2[r2][1] = dot2acc(wreg[r2 * 32 + j1], v.w, b2[r2][1]);
                    }
                }
#pragma unroll
                for (int bb2 = 0; bb2 < 2; ++bb2)
                    *(float2*)&psum[pidx][bb2][2 * lane] =
                        make_float2(a[0][bb2] + b2[0][bb2], a[1][bb2] + b2[1][bb2]);
            }
        } else {
            const uint4* hq = (w == 8 || w == 9) ? (const uint4*)&hown[(w - 8) * 64]
                                                 : (const uint4*)&priv[w][0];
            float a[2][2] = {{0.f, 0.f}, {0.f, 0.f}};
            float b2[2][2] = {{0.f, 0.f}, {0.f, 0.f}};
#pragma unroll
            for (int k = 0; k < 16; ++k) {
                uint4 v = hq[k];
                const int j0 = 2 * k, j1 = 2 * k + 1;
#pragma unroll
                for (int r2 = 0; r2 < 2; ++r2) {
                    a[r2][0]  = dot2acc(wreg[r2 * 32 + j0], v.x, a[r2][0]);
                    a[r2][1]  = dot2acc(wreg[r2 * 32 + j0], v.y, a[r2][1]);
                    b2[r2][0] = dot2acc(wreg[r2 * 32 + j1], v.z, b2[r2][0]);
                    b2[r2][1] = dot2acc(wreg[r2 * 32 + j1], v.w, b2[r2][1]);
                }
            }
#pragma unroll
            for (int bb2 = 0; bb2 < 2; ++bb2)
                *(float2*)&psum[w][bb2][2 * lane] =
                    make_float2(a[0][bb2] + b2[0][bb2], a[1][bb2] + b2[1][bb2]);
        }

        bar_lgkm();                                       // barrier b: psum ready (LDS only)

        // ---- reduce + tanh + post + own write ----
        if (isRed) {
            constexpr int NCH = (LAYER == 0) ? 10 : 16;
            float sum = 0.f;
#pragma unroll
            for (int ch = 0; ch < NCH; ++ch) sum += psum[ch][bbr][rw];
            float h = fast_tanh(sum + cb + nz);
            float hnb = __shfl_down(h, 1);
            if ((L & 1) == 0) {
                unsigned pv = pack2(h, hnb);
                int pr = s * 64 + (rw >> 1);
                unsigned long long atom =
                    ((unsigned long long)(tagbase + (unsigned)t + 1) << 32) |
                    (unsigned long long)pv;
                if constexpr (LAYER == 0) {
                    if (t - known > THR_LEAD) {           // ring-overwrite throttle
                        __builtin_amdgcn_s_setprio(0);
                        while (t - known > THR_LEAD && budget > 0) {
                            known = __hip_atomic_load(&prog[pair], __ATOMIC_RELAXED,
                                                      __HIP_MEMORY_SCOPE_AGENT);
                            --budget;
                        }
                        __builtin_amdgcn_s_setprio(1);
                    }
                    __hip_atomic_store(&hb0[((size_t)(t & (DRING - 1)) * NBATCH + (b0 + bbr)) * 256 + pr],
                                       atom, __ATOMIC_RELAXED, __HIP_MEMORY_SCOPE_AGENT);
                } else {
                    __hip_atomic_store(&hb1[((size_t)(t & 3) * NBATCH + (b0 + bbr)) * 256 + pr],
                                       atom, __ATOMIC_RELAXED, __HIP_MEMORY_SCOPE_AGENT);
                }
                hown[(rw >> 1) * 2 + bbr] = pv;
            }
            nz = nznext;
        }
        if constexpr (LAYER == 1) {                       // consumer progress
            if (s == 0 && L == 960 && t > 1)
                __hip_atomic_store(&prog[pair], t - 2, __ATOMIC_RELAXED,
                                   __HIP_MEMORY_SCOPE_AGENT);
        }
        bar_lgkm();                                       // barrier c: hown/psum safe
        __builtin_amdgcn_s_setprio(0);

        // ---- bottom-of-step: prefetch remote-h for t+1 (sibs just posted) ----
        if (!last) {
            if constexpr (LAYER == 1) {
                if (w >= 10) {
                    const int j = lane & 31, bbl = lane >> 5;
                    int m = (w - 10) * 32 + j;
                    int p2 = (m < s * 64) ? m : m + 64;
                    pfR = __hip_atomic_load(&hb1[((size_t)(t & 3) * NBATCH + (b0 + bbl)) * 256 + p2],
                                            __ATOMIC_RELAXED, __HIP_MEMORY_SCOPE_AGENT);
                }
            } else {
                if (w < 12 && lane < 32) {
                    int q = w >> 1, bbw = w & 1;
                    int m = q * 32 + lane;
                    int p2 = (m < s * 64) ? m : m + 64;
                    pfR = __hip_atomic_load(&hb0[((size_t)(t & (DRING - 1)) * NBATCH +
                                                  (b0 + bbw)) * 256 + p2],
                                            __ATOMIC_RELAXED, __HIP_MEMORY_SCOPE_AGENT);
                }
            }
        }
    }

    // ---- FC epilogue: out = h1(T-1) @ fc_w^T + fc_b (L1 s==0 WGs) ----
    if constexpr (LAYER == 1) {
        if (s == 0) {
            __shared__ float hs[2][512];
            __shared__ float part[2][512];
            if (L < 512) {
                int bl = L >> 8, pr = L & 255;
                unsigned v = poll1(&hb1[((size_t)((T_STEPS - 1) & 3) * NBATCH + (b0 + bl)) * 256 + pr],
                                   tagbase + (unsigned)T_STEPS, budget);
                half2v h2 = __builtin_bit_cast(half2v, v);
                hs[bl][2 * pr] = (float)h2.x; hs[bl][2 * pr + 1] = (float)h2.y;
            }
            __syncthreads();
            {
                int bl = L >> 9, rest = L & 511, o = rest & 31, seg = rest >> 5;
                const float* wr = fcw + o * 512 + seg * 32;
                const float* hr = &hs[bl][seg * 32];
                float a = 0.f;
#pragma unroll
                for (int k = 0; k < 32; ++k) a = fmaf(wr[k], hr[k], a);
                part[bl][rest] = a;
            }
            __syncthreads();
            if (L < 64) {
                int bl = L >> 5, o = L & 31;
                float ssum = fcb[o];
#pragma unroll
                for (int sgi = 0; sgi < 16; ++sgi) ssum += part[bl][sgi * 32 + o];
                out[(b0 + bl) * 32 + o] = ssum;
            }
        }
    }
}

__global__ __launch_bounds__(1024, 4)
void rnn_dual(const float* __restrict__ x, const float* __restrict__ noise,
              const unsigned* __restrict__ wp0, const unsigned* __restrict__ wp1,
              const float* __restrict__ bih0, const float* __restrict__ bhh0,
              const float* __restrict__ bih1, const float* __restrict__ bhh1,
              const float* __restrict__ fcw, const float* __restrict__ fcb,
              unsigned long long* __restrict__ hb0,
              unsigned long long* __restrict__ hb1,
              int* __restrict__ prog,
              float* __restrict__ out) {
    const int L = threadIdx.x;
    const int gid = blockIdx.x;
    const int cl = gid & 63;             // cluster: layer*32 + pair
    const int s = gid >> 6;              // sibling quarter 0..3
    const int layer = cl >> 5;
    const int pair = cl & 31;
    const int b0 = pair * 2;             // gid%8 == cl%8: co-XCD (locality only)
    if (layer == 0)
        run_layer<0>(b0, s, L, pair, x, noise, wp0, bih0, bhh0,
                     hb0, hb1, prog, nullptr, nullptr, nullptr);
    else
        run_layer<1>(b0, s, L, pair, x, noise, wp1, bih1, bhh1,
                     hb0, hb1, prog, fcw, fcb, out);
}

extern "C" void kernel_launch(void* const* d_in, const int* in_sizes, int n_in,
                              void* d_out, int out_size, void* d_ws, size_t ws_size,
                              hipStream_t stream) {
    const float* x     = (const float*)d_in[0];
    const float* noise = (const float*)d_in[1];
    const float* Wih0  = (const float*)d_in[2];
    const float* Wih1  = (const float*)d_in[3];
    const float* Whh0  = (const float*)d_in[4];
    const float* Whh1  = (const float*)d_in[5];
    const float* bih0  = (const float*)d_in[6];
    const float* bih1  = (const float*)d_in[7];
    const float* bhh0  = (const float*)d_in[8];
    const float* bhh1  = (const float*)d_in[9];
    const float* fcw   = (const float*)d_in[10];
    const float* fcb   = (const float*)d_in[11];
    float* out = (float*)d_out;

    char* ws = (char*)d_ws;
    size_t o = 0;
    unsigned* wp0 = (unsigned*)(ws + o); o += (size_t)NW0 * 4;  // 640 KB
    unsigned* wp1 = (unsigned*)(ws + o); o += (size_t)NW1 * 4;  // 1 MB
    unsigned long long* hb0 = (unsigned long long*)(ws + o);
    o += (size_t)DRING * NBATCH * 256 * 8;                      // 33.5 MB ring
    unsigned long long* hb1 = (unsigned long long*)(ws + o);
    o += (size_t)4 * NBATCH * 256 * 8;                          // 512 KB ring
    int* prog = (int*)(ws + o); o += 33 * sizeof(int);          // prog + epoch

    const int total = NW0 + NW1;
    init_pack<<<(total + 255) / 256, 256, 0, stream>>>(Wih0, Whh0, Wih1, Whh1,
                                                       wp0, wp1, prog);
    rnn_dual<<<256, 1024, 0, stream>>>(x, noise, wp0, wp1, bih0, bhh0, bih1, bhh1,
                                       fcw, fcb, hb0, hb1, prog, out);
}